// Round 6
// baseline (4950.690 us; speedup 1.0000x reference)
//
#include <hip/hip_runtime.h>

#define B_ 64
#define T_ 512
#define D_ 32
#define U_ 512
#define SIGD 1056

typedef _Float16 half8 __attribute__((ext_vector_type(8)));
typedef float f32x4 __attribute__((ext_vector_type(4)));
typedef unsigned int u32x4 __attribute__((ext_vector_type(4)));
typedef unsigned short ushort_t;
typedef unsigned int uint_t;
typedef unsigned long long ull_t;

// ---- workspace layout (bytes) ----
#define SIG_OFF   0ull            // fp16 norm_sigs  [b*512+t][1056]           69,206,016
#define F_OFF     69206016ull     // fp16 f_all      [t][u][b]                 33,554,432
#define FLG_OFF   102760448ull    // REUSED: tagged h dbuf 2 x [64][256] x 8B    262,144
#define A_OFF     136314880ull    // fp32 a          [b][t][i]                  4,194,304
#define DX_OFF    140509184ull    // fp32 dx         [b][t][i]                  4,194,304
#define X16_OFF   144703488ull    // fp16 x          [t][b][i]                  2,097,152
#define R16_OFF   146800640ull    // fp16 [R;Wi]     [k=544][n=1536]            1,671,168
#define WF16_OFF  148471808ull    // fp16 Wf         [k=1056][n=512]            1,081,344

// ============ K0: dx / a / x16 precompute + zero tagged h buffer ============
__global__ __launch_bounds__(256) void k_prep(const float* __restrict__ x,
                                              _Float16* x16, float* a_buf, float* dx_buf,
                                              uint_t* hb2) {
  int b = blockIdx.x;
  int tid = threadIdx.x;
  if (b >= 64) {  // blocks 64..67: zero hb2 (65536 u32 = 256KB) — kills stale tags
    for (int gi = (b - 64) * 256 + tid; gi < 65536; gi += 1024) hb2[gi] = 0u;
    return;
  }
  if (tid >= 32) return;
  int i = tid;
  float xprev = x[(b * T_) * D_ + i];
  x16[(0 * B_ + b) * D_ + i] = (_Float16)xprev;
  a_buf[(b * T_) * D_ + i] = 0.f;
  dx_buf[(b * T_) * D_ + i] = 0.f;
  float S1 = 0.f;
  for (int t = 1; t < T_; ++t) {
    float xv = x[(b * T_ + t) * D_ + i];
    float dx = xv - xprev;
    float a = S1 + 0.5f * dx;
    S1 += dx;
    a_buf[(b * T_ + t) * D_ + i] = a;
    dx_buf[(b * T_ + t) * D_ + i] = dx;
    x16[(t * B_ + b) * D_ + i] = (_Float16)xv;
    xprev = xv;
  }
}

// ============ K0b: weight fp16 conversion ============
__global__ __launch_bounds__(256) void k_weights(const float* __restrict__ rk,
                                                 const float* __restrict__ ik,
                                                 const float* __restrict__ fk,
                                                 _Float16* R16t, _Float16* Wf16) {
  int e = (blockIdx.x * 256 + threadIdx.x) * 4;
  if (e < 835584) {
    const float* src = (e < 786432) ? (rk + e) : (ik + (e - 786432));
#pragma unroll
    for (int j = 0; j < 4; ++j) R16t[e + j] = (_Float16)src[j];
  } else {
    int e2 = e - 835584;  // < 540672
#pragma unroll
    for (int j = 0; j < 4; ++j) Wf16[e2 + j] = (_Float16)fk[e2 + j];
  }
}

// ============ K1: signature stream -> normalized fp16 sig matrix ============
__global__ __launch_bounds__(1024) void k_sig(const float* __restrict__ a_buf,
                                              const float* __restrict__ dx_buf,
                                              _Float16* __restrict__ sig) {
  int b = blockIdx.x;
  int tid = threadIdx.x;
  int i = tid >> 5, j = tid & 31;
  __shared__ float a_ch[32][32];
  __shared__ float dx_ch[32][32];
  float S2 = 0.f;
  for (int t0 = 0; t0 < T_; t0 += 32) {
    a_ch[i][j]  = a_buf[(b * T_ + t0 + i) * D_ + j];
    dx_ch[i][j] = dx_buf[(b * T_ + t0 + i) * D_ + j];
    __syncthreads();
#pragma unroll 4
    for (int tt = 0; tt < 32; ++tt) {
      int t = t0 + tt;
      S2 += a_ch[tt][i] * dx_ch[tt][j];
      float inv = (t == 0) ? 0.f : (1.0f / (float)t);
      int row = b * T_ + t;
      sig[row * SIGD + 32 + i * 32 + j] = (_Float16)(S2 * inv);
      if (i == 0) {
        float s1 = a_ch[tt][j] + 0.5f * dx_ch[tt][j];
        sig[row * SIGD + j] = (_Float16)(s1 * inv);
      }
    }
    __syncthreads();
  }
}

// ============ K2: f_all = sigmoid(sig @ Wf + b_f), fp16 MFMA, out [t][u][b] ============
__global__ __launch_bounds__(256) void k_fgemm(const _Float16* __restrict__ sig,
                                               const _Float16* __restrict__ Wf16,
                                               const float* __restrict__ bias,
                                               _Float16* __restrict__ f_buf) {
  const int tid = threadIdx.x;
  const int m0 = blockIdx.x * 64;
  const int n0 = blockIdx.y * 128;
  __shared__ __align__(16) ushort_t As[64 * 40];
  __shared__ __align__(16) ushort_t Bs[128 * 40];
  const uint_t* sig32 = (const uint_t*)sig;
  const uint_t* w32 = (const uint_t*)Wf16;
  f32x4 acc[8];
#pragma unroll
  for (int nt = 0; nt < 8; ++nt) acc[nt] = f32x4{0.f, 0.f, 0.f, 0.f};
  const int lane = tid & 63, w = tid >> 6;
  const int cl = lane & 15, q8 = (lane >> 4) * 8;
  for (int kt = 0; kt < 33; ++kt) {
#pragma unroll
    for (int it = 0; it < 4; ++it) {
      int idx = tid + (it << 8);
      int row = idx >> 4, kp = idx & 15;
      uint_t v = sig32[(m0 + row) * 528 + kt * 16 + kp];
      *(uint_t*)&As[row * 40 + kp * 2] = v;
    }
#pragma unroll
    for (int it = 0; it < 8; ++it) {
      int idx = tid + (it << 8);
      int kr = idx >> 6, np = idx & 63;
      uint_t v = w32[(kt * 32 + kr) * 256 + (n0 >> 1) + np];
      Bs[(np * 2) * 40 + kr] = (ushort_t)(v & 0xffffu);
      Bs[(np * 2 + 1) * 40 + kr] = (ushort_t)(v >> 16);
    }
    __syncthreads();
    half8 a = *(const half8*)&As[(w * 16 + cl) * 40 + q8];
#pragma unroll
    for (int nt = 0; nt < 8; ++nt) {
      half8 bfr = *(const half8*)&Bs[(nt * 16 + cl) * 40 + q8];
      acc[nt] = __builtin_amdgcn_mfma_f32_16x16x32_f16(a, bfr, acc[nt], 0, 0, 0);
    }
    __syncthreads();
  }
#pragma unroll
  for (int nt = 0; nt < 8; ++nt) {
    int col = n0 + nt * 16 + cl;
    float bf = bias[512 + col];
#pragma unroll
    for (int r = 0; r < 4; ++r) {
      int m = m0 + w * 16 + ((lane >> 4) << 2) + r;
      int t = m & 511, b = m >> 9;
      float z = acc[nt][r] + bf;
      float fv = 1.f / (1.f + __expf(-z));
      f_buf[(t * 512 + col) * 64 + b] = (_Float16)fv;
    }
  }
}

// ============ K3: batch-partitioned persistent LSTM scan ============
// 64 blocks = 8 groups (G = bid&7). R6: FLAG-FREE tagged-data exchange.
// Each h-pair is stored as one ATOMIC 8B entry (packed_h32 | (t+1)<<32) via
// agent-scope store (LLC). Consumers batch-gather 32 x dwordx4 (sc0 sc1,
// R5-proven coherent vs agent stores) and retry until all 64 tags == t.
// This deletes 3 serial LLC hops/step of the old protocol (store drain,
// flag store, flag poll): critical path = store one-way + gather RTT +
// compute. Tag monotonicity makes it a proper step barrier (no wave enters
// t+1 before all finished t => no buffer overwrite race; 8B atomicity =>
// tag never precedes data). Retries bounded (bail-forward, R4 discipline).
__global__ __launch_bounds__(256, 1) void k_scan(const _Float16* __restrict__ R16t,
                                                 const float* __restrict__ bias,
                                                 const _Float16* __restrict__ f16,
                                                 const _Float16* __restrict__ x16,
                                                 uint_t* hb2,
                                                 float* __restrict__ out) {
  const int tid = threadIdx.x;
  const int bid = blockIdx.x;         // 0..63
  const int G = bid & 7;              // group (batch tile)
  const int mj = bid >> 3;            // member block 0..7
  const int lane = tid & 63, w = tid >> 6;
  const int cl = lane & 15, quad = lane >> 4, q8 = quad * 8;
  const int widx = (mj << 2) | w;     // producer-wave index in group, 0..31
  const int u0 = widx * 16;           // unit tile base
  const int u = u0 + cl;              // this lane's unit
  const int b0 = G * 8;               // batch base
  const int arow = b0 + (cl & 7);     // A-frag batch row (rows 8..15 duplicate)

  // B fragments: 3 gates (i,c,o) x 17 ksteps = 204 VGPRs
  half8 bfr[3][17];
#pragma unroll
  for (int g3 = 0; g3 < 3; ++g3)
#pragma unroll
    for (int kk = 0; kk < 17; ++kk)
#pragma unroll
      for (int jj = 0; jj < 8; ++jj)
        bfr[g3][kk][jj] = R16t[(kk * 32 + q8 + jj) * 1536 + g3 * 512 + u];

  const float bi = bias[u];
  const float bc = bias[1024 + u];
  const float bo = bias[1536 + u];
  float c_st[4] = {0.f, 0.f, 0.f, 0.f};

  // tagged h double buffer: buf(t written) = (t&1)? base+0 : base+131072
  // entry (row, unit-pair): byte = row*2048 + unit*4  (8B = packed|tag)
#pragma unroll 1
  for (int t = 0; t < T_; ++t) {
    char* wb = (char*)hb2 + ((t & 1) ? 0 : 131072);
    const char* rbase = (const char*)hb2 + ((t & 1) ? 131072 : 0);
    const char* addr = rbase + arow * 2048 + q8 * 4;

    u32x4 g2[32];
#define GLD2(i, off) \
    asm volatile("global_load_dwordx4 %0, %1, off offset:" #off " sc0 sc1" \
                 : "=&v"(g2[i]) : "v"(addr))
#define ISSUE32() do { \
    GLD2(0, 0);     GLD2(1, 16);    GLD2(2, 128);   GLD2(3, 144);   \
    GLD2(4, 256);   GLD2(5, 272);   GLD2(6, 384);   GLD2(7, 400);   \
    GLD2(8, 512);   GLD2(9, 528);   GLD2(10, 640);  GLD2(11, 656);  \
    GLD2(12, 768);  GLD2(13, 784);  GLD2(14, 896);  GLD2(15, 912);  \
    GLD2(16, 1024); GLD2(17, 1040); GLD2(18, 1152); GLD2(19, 1168); \
    GLD2(20, 1280); GLD2(21, 1296); GLD2(22, 1408); GLD2(23, 1424); \
    GLD2(24, 1536); GLD2(25, 1552); GLD2(26, 1664); GLD2(27, 1680); \
    GLD2(28, 1792); GLD2(29, 1808); GLD2(30, 1920); GLD2(31, 1936); \
  } while (0)

    if (t > 0) ISSUE32();   // in flight while fpre/xa load below

    // ---- t-dependent, h-independent data: latency hides under gather RTT ----
    float fpre[4];
    {
      union { ull_t q; _Float16 h[4]; } fu;
      fu.q = *(const ull_t*)(f16 + ((t * 512 + u) * 64 + b0 + (quad & 1) * 4));
#pragma unroll
      for (int r = 0; r < 4; ++r) fpre[r] = (float)fu.h[r];
    }
    half8 xa = *(const half8*)(x16 + ((t * 64 + arow) * 32 + q8));

    if (t > 0) {
      const uint_t texp = (uint_t)t;  // producers at t-1 stored tag t
      for (int it = 0; ; ++it) {
        asm volatile("s_waitcnt vmcnt(0)" ::: "memory");
        __builtin_amdgcn_sched_barrier(0);
        uint_t bad = 0;
#pragma unroll
        for (int i = 0; i < 32; ++i)
          bad |= (g2[i][1] ^ texp) | (g2[i][3] ^ texp);
        if (__all(bad == 0u)) break;
        if (it >= 4000) break;        // bail-forward: terminating, diagnosable
        ISSUE32();
      }
    } else {
#pragma unroll
      for (int i = 0; i < 32; ++i) g2[i] = u32x4{0u, 0u, 0u, 0u};
    }
#undef ISSUE32
#undef GLD2

    // ---- 51 MFMAs: i, c, o (A frags assembled from tagged pairs) ----
    f32x4 ai = f32x4{0.f, 0.f, 0.f, 0.f};
    f32x4 ac = f32x4{0.f, 0.f, 0.f, 0.f};
    f32x4 ao = f32x4{0.f, 0.f, 0.f, 0.f};
#pragma unroll
    for (int kk = 0; kk < 16; ++kk) {
      u32x4 lo = g2[2 * kk], hi = g2[2 * kk + 1];
      u32x4 av = u32x4{lo[0], lo[2], hi[0], hi[2]};
      half8 af = __builtin_bit_cast(half8, av);
      ai = __builtin_amdgcn_mfma_f32_16x16x32_f16(af, bfr[0][kk], ai, 0, 0, 0);
      ac = __builtin_amdgcn_mfma_f32_16x16x32_f16(af, bfr[1][kk], ac, 0, 0, 0);
      ao = __builtin_amdgcn_mfma_f32_16x16x32_f16(af, bfr[2][kk], ao, 0, 0, 0);
    }
    ai = __builtin_amdgcn_mfma_f32_16x16x32_f16(xa, bfr[0][16], ai, 0, 0, 0);
    ac = __builtin_amdgcn_mfma_f32_16x16x32_f16(xa, bfr[1][16], ac, 0, 0, 0);
    ao = __builtin_amdgcn_mfma_f32_16x16x32_f16(xa, bfr[2][16], ao, 0, 0, 0);

    // ---- epilogue: gates -> c,h; publish tagged h (no drain, no flag) ----
#pragma unroll
    for (int r = 0; r < 4; ++r) {
      int brow = (quad << 2) + r;   // local batch row 0..15, valid < 8
      float iv = 1.f / (1.f + __expf(-(ai[r] + bi)));
      float cv = 1.f - 2.f / (__expf(2.f * (ac[r] + bc)) + 1.f);
      float ov = 1.f / (1.f + __expf(-(ao[r] + bo)));
      float c = fpre[r] * c_st[r] + iv * cv;
      c_st[r] = c;
      float h = ov * (1.f - 2.f / (__expf(2.f * c) + 1.f));
      if (t < T_ - 1) {
        ushort_t hu = __builtin_bit_cast(ushort_t, (_Float16)h);
        uint_t nbr = (uint_t)(unsigned)__shfl_xor((int)hu, 1);
        uint_t packed = ((uint_t)hu & 0xffffu) | (nbr << 16);
        if (brow < 8 && !(cl & 1)) {
          ull_t pk = (ull_t)packed | ((ull_t)(uint_t)(t + 1) << 32);
          ull_t* p = (ull_t*)(wb + (b0 + brow) * 2048 + (u0 + cl) * 4);
          __hip_atomic_store(p, pk, __ATOMIC_RELAXED, __HIP_MEMORY_SCOPE_AGENT);
        }
      } else {
        if (brow < 8) out[((b0 + brow) << 9) + u] = h;
      }
    }
    // no trailing drain: tags self-synchronize; stores ack asynchronously
  }
}

extern "C" void kernel_launch(void* const* d_in, const int* in_sizes, int n_in,
                              void* d_out, int out_size, void* d_ws, size_t ws_size,
                              hipStream_t stream) {
  const float* x = (const float*)d_in[0];
  const float* ik = (const float*)d_in[1];
  const float* rk = (const float*)d_in[2];
  const float* fk = (const float*)d_in[3];
  const float* bias = (const float*)d_in[4];
  char* ws = (char*)d_ws;
  _Float16* sig = (_Float16*)(ws + SIG_OFF);
  _Float16* f_buf = (_Float16*)(ws + F_OFF);
  uint_t* hb2 = (uint_t*)(ws + FLG_OFF);
  float* a_buf = (float*)(ws + A_OFF);
  float* dx_buf = (float*)(ws + DX_OFF);
  _Float16* x16 = (_Float16*)(ws + X16_OFF);
  _Float16* R16t = (_Float16*)(ws + R16_OFF);
  _Float16* Wf16 = (_Float16*)(ws + WF16_OFF);
  float* out = (float*)d_out;

  hipLaunchKernelGGL(k_prep, dim3(68), dim3(256), 0, stream, x, x16, a_buf, dx_buf, hb2);
  hipLaunchKernelGGL(k_weights, dim3(1344), dim3(256), 0, stream, rk, ik, fk, R16t, Wf16);
  hipLaunchKernelGGL(k_sig, dim3(64), dim3(1024), 0, stream, a_buf, dx_buf, sig);
  hipLaunchKernelGGL(k_fgemm, dim3(512, 4), dim3(256), 0, stream, sig, Wf16, bias, f_buf);
  hipLaunchKernelGGL(k_scan, dim3(64), dim3(256), 0, stream, R16t, bias, f_buf,
                     x16, hb2, out);
}

// Round 7
// 3754.850 us; speedup vs baseline: 1.3185x; 1.3185x over previous
//
#include <hip/hip_runtime.h>

#define B_ 64
#define T_ 512
#define D_ 32
#define U_ 512
#define SIGD 1056

typedef _Float16 half8 __attribute__((ext_vector_type(8)));
typedef float f32x4 __attribute__((ext_vector_type(4)));
typedef unsigned int u32x4 __attribute__((ext_vector_type(4)));
typedef unsigned short ushort_t;
typedef unsigned int uint_t;
typedef unsigned long long ull_t;

// ---- workspace layout (bytes) ----
#define SIG_OFF   0ull            // fp16 norm_sigs  [b*512+t][1056]           69,206,016
#define F_OFF     69206016ull     // fp16 f_all      [t][u][b]                 33,554,432
#define FLG_OFF   102760448ull    // u32 flags [(t*8+G)*32 + wave]                524,288
#define HB2_OFF   103284736ull    // tagged h dbuf 2 x [64 rows][256 pairs] x 8B  262,144
#define A_OFF     136314880ull    // fp32 a          [b][t][i]                  4,194,304
#define DX_OFF    140509184ull    // fp32 dx         [b][t][i]                  4,194,304
#define X16_OFF   144703488ull    // fp16 x          [t][b][i]                  2,097,152
#define R16_OFF   146800640ull    // fp16 [R;Wi]     [k=544][n=1536]            1,671,168
#define WF16_OFF  148471808ull    // fp16 Wf         [k=1056][n=512]            1,081,344

// ============ K0: dx / a / x16 precompute + zero flg/hb2 ============
__global__ __launch_bounds__(256) void k_prep(const float* __restrict__ x,
                                              _Float16* x16, float* a_buf, float* dx_buf,
                                              uint_t* flg, uint_t* hb2) {
  int b = blockIdx.x;
  int tid = threadIdx.x;
  if (b >= 64) {  // blocks 64..67: zero flg (131072 u32) + hb2 (65536 u32)
    for (int gi = (b - 64) * 256 + tid; gi < 196608; gi += 1024) {
      if (gi < 131072) flg[gi] = 0u;
      else hb2[gi - 131072] = 0u;
    }
    return;
  }
  if (tid >= 32) return;
  int i = tid;
  float xprev = x[(b * T_) * D_ + i];
  x16[(0 * B_ + b) * D_ + i] = (_Float16)xprev;
  a_buf[(b * T_) * D_ + i] = 0.f;
  dx_buf[(b * T_) * D_ + i] = 0.f;
  float S1 = 0.f;
  for (int t = 1; t < T_; ++t) {
    float xv = x[(b * T_ + t) * D_ + i];
    float dx = xv - xprev;
    float a = S1 + 0.5f * dx;
    S1 += dx;
    a_buf[(b * T_ + t) * D_ + i] = a;
    dx_buf[(b * T_ + t) * D_ + i] = dx;
    x16[(t * B_ + b) * D_ + i] = (_Float16)xv;
    xprev = xv;
  }
}

// ============ K0b: weight fp16 conversion ============
__global__ __launch_bounds__(256) void k_weights(const float* __restrict__ rk,
                                                 const float* __restrict__ ik,
                                                 const float* __restrict__ fk,
                                                 _Float16* R16t, _Float16* Wf16) {
  int e = (blockIdx.x * 256 + threadIdx.x) * 4;
  if (e < 835584) {
    const float* src = (e < 786432) ? (rk + e) : (ik + (e - 786432));
#pragma unroll
    for (int j = 0; j < 4; ++j) R16t[e + j] = (_Float16)src[j];
  } else {
    int e2 = e - 835584;  // < 540672
#pragma unroll
    for (int j = 0; j < 4; ++j) Wf16[e2 + j] = (_Float16)fk[e2 + j];
  }
}

// ============ K1: signature stream -> normalized fp16 sig matrix ============
__global__ __launch_bounds__(1024) void k_sig(const float* __restrict__ a_buf,
                                              const float* __restrict__ dx_buf,
                                              _Float16* __restrict__ sig) {
  int b = blockIdx.x;
  int tid = threadIdx.x;
  int i = tid >> 5, j = tid & 31;
  __shared__ float a_ch[32][32];
  __shared__ float dx_ch[32][32];
  float S2 = 0.f;
  for (int t0 = 0; t0 < T_; t0 += 32) {
    a_ch[i][j]  = a_buf[(b * T_ + t0 + i) * D_ + j];
    dx_ch[i][j] = dx_buf[(b * T_ + t0 + i) * D_ + j];
    __syncthreads();
#pragma unroll 4
    for (int tt = 0; tt < 32; ++tt) {
      int t = t0 + tt;
      S2 += a_ch[tt][i] * dx_ch[tt][j];
      float inv = (t == 0) ? 0.f : (1.0f / (float)t);
      int row = b * T_ + t;
      sig[row * SIGD + 32 + i * 32 + j] = (_Float16)(S2 * inv);
      if (i == 0) {
        float s1 = a_ch[tt][j] + 0.5f * dx_ch[tt][j];
        sig[row * SIGD + j] = (_Float16)(s1 * inv);
      }
    }
    __syncthreads();
  }
}

// ============ K2: f_all = sigmoid(sig @ Wf + b_f), fp16 MFMA, out [t][u][b] ============
__global__ __launch_bounds__(256) void k_fgemm(const _Float16* __restrict__ sig,
                                               const _Float16* __restrict__ Wf16,
                                               const float* __restrict__ bias,
                                               _Float16* __restrict__ f_buf) {
  const int tid = threadIdx.x;
  const int m0 = blockIdx.x * 64;
  const int n0 = blockIdx.y * 128;
  __shared__ __align__(16) ushort_t As[64 * 40];
  __shared__ __align__(16) ushort_t Bs[128 * 40];
  const uint_t* sig32 = (const uint_t*)sig;
  const uint_t* w32 = (const uint_t*)Wf16;
  f32x4 acc[8];
#pragma unroll
  for (int nt = 0; nt < 8; ++nt) acc[nt] = f32x4{0.f, 0.f, 0.f, 0.f};
  const int lane = tid & 63, w = tid >> 6;
  const int cl = lane & 15, q8 = (lane >> 4) * 8;
  for (int kt = 0; kt < 33; ++kt) {
#pragma unroll
    for (int it = 0; it < 4; ++it) {
      int idx = tid + (it << 8);
      int row = idx >> 4, kp = idx & 15;
      uint_t v = sig32[(m0 + row) * 528 + kt * 16 + kp];
      *(uint_t*)&As[row * 40 + kp * 2] = v;
    }
#pragma unroll
    for (int it = 0; it < 8; ++it) {
      int idx = tid + (it << 8);
      int kr = idx >> 6, np = idx & 63;
      uint_t v = w32[(kt * 32 + kr) * 256 + (n0 >> 1) + np];
      Bs[(np * 2) * 40 + kr] = (ushort_t)(v & 0xffffu);
      Bs[(np * 2 + 1) * 40 + kr] = (ushort_t)(v >> 16);
    }
    __syncthreads();
    half8 a = *(const half8*)&As[(w * 16 + cl) * 40 + q8];
#pragma unroll
    for (int nt = 0; nt < 8; ++nt) {
      half8 bfr = *(const half8*)&Bs[(nt * 16 + cl) * 40 + q8];
      acc[nt] = __builtin_amdgcn_mfma_f32_16x16x32_f16(a, bfr, acc[nt], 0, 0, 0);
    }
    __syncthreads();
  }
#pragma unroll
  for (int nt = 0; nt < 8; ++nt) {
    int col = n0 + nt * 16 + cl;
    float bf = bias[512 + col];
#pragma unroll
    for (int r = 0; r < 4; ++r) {
      int m = m0 + w * 16 + ((lane >> 4) << 2) + r;
      int t = m & 511, b = m >> 9;
      float z = acc[nt][r] + bf;
      float fv = 1.f / (1.f + __expf(-z));
      f_buf[(t * 512 + col) * 64 + b] = (_Float16)fv;
    }
  }
}

// ============ K3: batch-partitioned persistent LSTM scan ============
// 64 blocks = 8 groups (G = bid&7). R7 protocol = R5 minus the producer
// drain: publish h as tagged 8B atomic entries (R6-proven format, tag=t+1),
// store the advisory flag IMMEDIATELY (no vmcnt drain — the ~2.5k cy drain
// was serial before the flag and overlapped with nothing). Consumer: skinny
// flag poll (R5-proven, 128B/wave/iter — R6 showed fat polling storms the
// LLC), then ONE fat tagged gather; embedded tags carry correctness (flag
// may beat data by store-pipeline skew only), bounded retry (expect 0-1).
__global__ __launch_bounds__(256, 1) void k_scan(const _Float16* __restrict__ R16t,
                                                 const float* __restrict__ bias,
                                                 const _Float16* __restrict__ f16,
                                                 const _Float16* __restrict__ x16,
                                                 uint_t* hb2, uint_t* flg,
                                                 float* __restrict__ out) {
  const int tid = threadIdx.x;
  const int bid = blockIdx.x;         // 0..63
  const int G = bid & 7;              // group (batch tile)
  const int mj = bid >> 3;            // member block 0..7
  const int lane = tid & 63, w = tid >> 6;
  const int cl = lane & 15, quad = lane >> 4, q8 = quad * 8;
  const int widx = (mj << 2) | w;     // producer-wave index in group, 0..31
  const int u0 = widx * 16;           // unit tile base
  const int u = u0 + cl;              // this lane's unit
  const int b0 = G * 8;               // batch base
  const int arow = b0 + (cl & 7);     // A-frag batch row (rows 8..15 duplicate)

  // B fragments: 3 gates (i,c,o) x 17 ksteps = 204 VGPRs
  half8 bfr[3][17];
#pragma unroll
  for (int g3 = 0; g3 < 3; ++g3)
#pragma unroll
    for (int kk = 0; kk < 17; ++kk)
#pragma unroll
      for (int jj = 0; jj < 8; ++jj)
        bfr[g3][kk][jj] = R16t[(kk * 32 + q8 + jj) * 1536 + g3 * 512 + u];

  const float bi = bias[u];
  const float bc = bias[1024 + u];
  const float bo = bias[1536 + u];
  float c_st[4] = {0.f, 0.f, 0.f, 0.f};

  // tagged h dbuf: write parity (t&1)? +0 : +131072; read opposite.
  // entry (row, even-unit): byte = row*2048 + unit*4  (8B = packed|tag)
#pragma unroll 1
  for (int t = 0; t < T_; ++t) {
    char* wb = (char*)hb2 + ((t & 1) ? 0 : 131072);
    const char* addr = (const char*)hb2 + ((t & 1) ? 131072 : 0) + arow * 2048 + q8 * 4;

    // ---- t-dependent, h-independent prefetch (before the wait) ----
    float fpre[4];
    {
      union { ull_t q; _Float16 h[4]; } fu;
      fu.q = *(const ull_t*)(f16 + ((t * 512 + u) * 64 + b0 + (quad & 1) * 4));
#pragma unroll
      for (int r = 0; r < 4; ++r) fpre[r] = (float)fu.h[r];
    }
    half8 xa = *(const half8*)(x16 + ((t * 64 + arow) * 32 + q8));

    u32x4 g2[32];
#define GLD2(i, off) \
    asm volatile("global_load_dwordx4 %0, %1, off offset:" #off " sc0 sc1" \
                 : "=&v"(g2[i]) : "v"(addr))
#define ISSUE32() do { \
    GLD2(0, 0);     GLD2(1, 16);    GLD2(2, 128);   GLD2(3, 144);   \
    GLD2(4, 256);   GLD2(5, 272);   GLD2(6, 384);   GLD2(7, 400);   \
    GLD2(8, 512);   GLD2(9, 528);   GLD2(10, 640);  GLD2(11, 656);  \
    GLD2(12, 768);  GLD2(13, 784);  GLD2(14, 896);  GLD2(15, 912);  \
    GLD2(16, 1024); GLD2(17, 1040); GLD2(18, 1152); GLD2(19, 1168); \
    GLD2(20, 1280); GLD2(21, 1296); GLD2(22, 1408); GLD2(23, 1424); \
    GLD2(24, 1536); GLD2(25, 1552); GLD2(26, 1664); GLD2(27, 1680); \
    GLD2(28, 1792); GLD2(29, 1808); GLD2(30, 1920); GLD2(31, 1936); \
  } while (0)

    if (t > 0) {
      // ---- skinny flag poll: tight-spin first 8 iters, then sleepy ----
      const uint_t* fp = flg + (((t - 1) * 8 + G) << 5) + (lane & 31);
      int spins = 0;
      for (;;) {
        uint_t v = 1u;
        if (lane < 32)
          v = __hip_atomic_load(fp, __ATOMIC_RELAXED, __HIP_MEMORY_SCOPE_AGENT);
        if (__all(v != 0u)) break;
        if (++spins > 8) __builtin_amdgcn_s_sleep(1);
      }
      // ---- fat tagged gather; tags carry correctness; bounded retry ----
      const uint_t texp = (uint_t)t;  // producers at t-1 stored tag t
      for (int it = 0; ; ++it) {
        ISSUE32();
        asm volatile("s_waitcnt vmcnt(0)" ::: "memory");
        __builtin_amdgcn_sched_barrier(0);
        uint_t bad = 0;
#pragma unroll
        for (int i = 0; i < 32; ++i)
          bad |= (g2[i][1] ^ texp) | (g2[i][3] ^ texp);
        if (__all(bad == 0u)) break;
        if (it >= 256) break;         // bail-forward: terminating, diagnosable
      }
    } else {
#pragma unroll
      for (int i = 0; i < 32; ++i) g2[i] = u32x4{0u, 0u, 0u, 0u};
    }
#undef ISSUE32
#undef GLD2

    // ---- 51 MFMAs: i, c, o (A frags from tagged pairs) ----
    f32x4 ai = f32x4{0.f, 0.f, 0.f, 0.f};
    f32x4 ac = f32x4{0.f, 0.f, 0.f, 0.f};
    f32x4 ao = f32x4{0.f, 0.f, 0.f, 0.f};
#pragma unroll
    for (int kk = 0; kk < 16; ++kk) {
      u32x4 lo = g2[2 * kk], hi = g2[2 * kk + 1];
      u32x4 av = u32x4{lo[0], lo[2], hi[0], hi[2]};
      half8 af = __builtin_bit_cast(half8, av);
      ai = __builtin_amdgcn_mfma_f32_16x16x32_f16(af, bfr[0][kk], ai, 0, 0, 0);
      ac = __builtin_amdgcn_mfma_f32_16x16x32_f16(af, bfr[1][kk], ac, 0, 0, 0);
      ao = __builtin_amdgcn_mfma_f32_16x16x32_f16(af, bfr[2][kk], ao, 0, 0, 0);
    }
    ai = __builtin_amdgcn_mfma_f32_16x16x32_f16(xa, bfr[0][16], ai, 0, 0, 0);
    ac = __builtin_amdgcn_mfma_f32_16x16x32_f16(xa, bfr[1][16], ac, 0, 0, 0);
    ao = __builtin_amdgcn_mfma_f32_16x16x32_f16(xa, bfr[2][16], ao, 0, 0, 0);

    // ---- epilogue: gates -> c,h; tagged publish, then advisory flag ----
#pragma unroll
    for (int r = 0; r < 4; ++r) {
      int brow = (quad << 2) + r;   // local batch row 0..15, valid < 8
      float iv = 1.f / (1.f + __expf(-(ai[r] + bi)));
      float cv = 1.f - 2.f / (__expf(2.f * (ac[r] + bc)) + 1.f);
      float ov = 1.f / (1.f + __expf(-(ao[r] + bo)));
      float c = fpre[r] * c_st[r] + iv * cv;
      c_st[r] = c;
      float h = ov * (1.f - 2.f / (__expf(2.f * c) + 1.f));
      if (t < T_ - 1) {
        ushort_t hu = __builtin_bit_cast(ushort_t, (_Float16)h);
        uint_t nbr = (uint_t)(unsigned)__shfl_xor((int)hu, 1);
        uint_t packed = ((uint_t)hu & 0xffffu) | (nbr << 16);
        if (brow < 8 && !(cl & 1)) {
          ull_t pk = (ull_t)packed | ((ull_t)(uint_t)(t + 1) << 32);
          ull_t* p = (ull_t*)(wb + (b0 + brow) * 2048 + (u0 + cl) * 4);
          __hip_atomic_store(p, pk, __ATOMIC_RELAXED, __HIP_MEMORY_SCOPE_AGENT);
        }
      } else {
        if (brow < 8) out[((b0 + brow) << 9) + u] = h;
      }
    }
    // advisory flag — NO drain (tags in data carry correctness)
    if (lane == 0 && t < T_ - 1)
      __hip_atomic_store(&flg[((t * 8 + G) << 5) + widx], 1u, __ATOMIC_RELAXED,
                         __HIP_MEMORY_SCOPE_AGENT);
  }
}

extern "C" void kernel_launch(void* const* d_in, const int* in_sizes, int n_in,
                              void* d_out, int out_size, void* d_ws, size_t ws_size,
                              hipStream_t stream) {
  const float* x = (const float*)d_in[0];
  const float* ik = (const float*)d_in[1];
  const float* rk = (const float*)d_in[2];
  const float* fk = (const float*)d_in[3];
  const float* bias = (const float*)d_in[4];
  char* ws = (char*)d_ws;
  _Float16* sig = (_Float16*)(ws + SIG_OFF);
  _Float16* f_buf = (_Float16*)(ws + F_OFF);
  uint_t* flg = (uint_t*)(ws + FLG_OFF);
  uint_t* hb2 = (uint_t*)(ws + HB2_OFF);
  float* a_buf = (float*)(ws + A_OFF);
  float* dx_buf = (float*)(ws + DX_OFF);
  _Float16* x16 = (_Float16*)(ws + X16_OFF);
  _Float16* R16t = (_Float16*)(ws + R16_OFF);
  _Float16* Wf16 = (_Float16*)(ws + WF16_OFF);
  float* out = (float*)d_out;

  hipLaunchKernelGGL(k_prep, dim3(68), dim3(256), 0, stream, x, x16, a_buf, dx_buf, flg, hb2);
  hipLaunchKernelGGL(k_weights, dim3(1344), dim3(256), 0, stream, rk, ik, fk, R16t, Wf16);
  hipLaunchKernelGGL(k_sig, dim3(64), dim3(1024), 0, stream, a_buf, dx_buf, sig);
  hipLaunchKernelGGL(k_fgemm, dim3(512, 4), dim3(256), 0, stream, sig, Wf16, bias, f_buf);
  hipLaunchKernelGGL(k_scan, dim3(64), dim3(256), 0, stream, R16t, bias, f_buf,
                     x16, hb2, flg, out);
}

// Round 8
// 2904.426 us; speedup vs baseline: 1.7045x; 1.2928x over previous
//
#include <hip/hip_runtime.h>

#define B_ 64
#define T_ 512
#define D_ 32
#define U_ 512
#define SIGD 1056

typedef _Float16 half8 __attribute__((ext_vector_type(8)));
typedef float f32x4 __attribute__((ext_vector_type(4)));
typedef unsigned short ushort_t;
typedef unsigned int uint_t;
typedef unsigned long long ull_t;

// ---- workspace layout (bytes) ----
#define SIG_OFF   0ull            // fp16 norm_sigs  [b*512+t][1056]           69,206,016
#define F_OFF     69206016ull     // fp16 f_all      [t][u][b]                 33,554,432
#define FLG_OFF   102760448ull    // u32 flags [(t*8+G)*32 + wave]                524,288
#define A_OFF     136314880ull    // fp32 a          [b][t][i]                  4,194,304
#define DX_OFF    140509184ull    // fp32 dx         [b][t][i]                  4,194,304
#define X16_OFF   144703488ull    // fp16 x          [t][b][i]                  2,097,152
#define R16_OFF   146800640ull    // fp16 [R;Wi]     [k=544][n=1536]            1,671,168
#define WF16_OFF  148471808ull    // fp16 Wf         [k=1056][n=512]            1,081,344
#define HB_OFF    149553152ull    // fp16 h double buffer: 2 x [64][512]          131,072

// ============ K0: dx / a / x16 precompute + zero hb/flg ============
__global__ __launch_bounds__(256) void k_prep(const float* __restrict__ x,
                                              _Float16* x16, float* a_buf, float* dx_buf,
                                              uint_t* hb, uint_t* flg) {
  int b = blockIdx.x;
  int tid = threadIdx.x;
  if (b >= 64) {  // blocks 64..67: zero hb(32768 u32) + flg(131072 u32)
    for (int gi = (b - 64) * 256 + tid; gi < 163840; gi += 1024) {
      if (gi < 32768) hb[gi] = 0u;
      else flg[gi - 32768] = 0u;
    }
    return;
  }
  if (tid >= 32) return;
  int i = tid;
  float xprev = x[(b * T_) * D_ + i];
  x16[(0 * B_ + b) * D_ + i] = (_Float16)xprev;
  a_buf[(b * T_) * D_ + i] = 0.f;
  dx_buf[(b * T_) * D_ + i] = 0.f;
  float S1 = 0.f;
  for (int t = 1; t < T_; ++t) {
    float xv = x[(b * T_ + t) * D_ + i];
    float dx = xv - xprev;
    float a = S1 + 0.5f * dx;
    S1 += dx;
    a_buf[(b * T_ + t) * D_ + i] = a;
    dx_buf[(b * T_ + t) * D_ + i] = dx;
    x16[(t * B_ + b) * D_ + i] = (_Float16)xv;
    xprev = xv;
  }
}

// ============ K0b: weight fp16 conversion ============
__global__ __launch_bounds__(256) void k_weights(const float* __restrict__ rk,
                                                 const float* __restrict__ ik,
                                                 const float* __restrict__ fk,
                                                 _Float16* R16t, _Float16* Wf16) {
  int e = (blockIdx.x * 256 + threadIdx.x) * 4;
  if (e < 835584) {
    const float* src = (e < 786432) ? (rk + e) : (ik + (e - 786432));
#pragma unroll
    for (int j = 0; j < 4; ++j) R16t[e + j] = (_Float16)src[j];
  } else {
    int e2 = e - 835584;  // < 540672
#pragma unroll
    for (int j = 0; j < 4; ++j) Wf16[e2 + j] = (_Float16)fk[e2 + j];
  }
}

// ============ K1: signature stream -> normalized fp16 sig matrix ============
__global__ __launch_bounds__(1024) void k_sig(const float* __restrict__ a_buf,
                                              const float* __restrict__ dx_buf,
                                              _Float16* __restrict__ sig) {
  int b = blockIdx.x;
  int tid = threadIdx.x;
  int i = tid >> 5, j = tid & 31;
  __shared__ float a_ch[32][32];
  __shared__ float dx_ch[32][32];
  float S2 = 0.f;
  for (int t0 = 0; t0 < T_; t0 += 32) {
    a_ch[i][j]  = a_buf[(b * T_ + t0 + i) * D_ + j];
    dx_ch[i][j] = dx_buf[(b * T_ + t0 + i) * D_ + j];
    __syncthreads();
#pragma unroll 4
    for (int tt = 0; tt < 32; ++tt) {
      int t = t0 + tt;
      S2 += a_ch[tt][i] * dx_ch[tt][j];
      float inv = (t == 0) ? 0.f : (1.0f / (float)t);
      int row = b * T_ + t;
      sig[row * SIGD + 32 + i * 32 + j] = (_Float16)(S2 * inv);
      if (i == 0) {
        float s1 = a_ch[tt][j] + 0.5f * dx_ch[tt][j];
        sig[row * SIGD + j] = (_Float16)(s1 * inv);
      }
    }
    __syncthreads();
  }
}

// ============ K2: f_all = sigmoid(sig @ Wf + b_f), fp16 MFMA, out [t][u][b] ============
__global__ __launch_bounds__(256) void k_fgemm(const _Float16* __restrict__ sig,
                                               const _Float16* __restrict__ Wf16,
                                               const float* __restrict__ bias,
                                               _Float16* __restrict__ f_buf) {
  const int tid = threadIdx.x;
  const int m0 = blockIdx.x * 64;
  const int n0 = blockIdx.y * 128;
  __shared__ __align__(16) ushort_t As[64 * 40];
  __shared__ __align__(16) ushort_t Bs[128 * 40];
  const uint_t* sig32 = (const uint_t*)sig;
  const uint_t* w32 = (const uint_t*)Wf16;
  f32x4 acc[8];
#pragma unroll
  for (int nt = 0; nt < 8; ++nt) acc[nt] = f32x4{0.f, 0.f, 0.f, 0.f};
  const int lane = tid & 63, w = tid >> 6;
  const int cl = lane & 15, q8 = (lane >> 4) * 8;
  for (int kt = 0; kt < 33; ++kt) {
#pragma unroll
    for (int it = 0; it < 4; ++it) {
      int idx = tid + (it << 8);
      int row = idx >> 4, kp = idx & 15;
      uint_t v = sig32[(m0 + row) * 528 + kt * 16 + kp];
      *(uint_t*)&As[row * 40 + kp * 2] = v;
    }
#pragma unroll
    for (int it = 0; it < 8; ++it) {
      int idx = tid + (it << 8);
      int kr = idx >> 6, np = idx & 63;
      uint_t v = w32[(kt * 32 + kr) * 256 + (n0 >> 1) + np];
      Bs[(np * 2) * 40 + kr] = (ushort_t)(v & 0xffffu);
      Bs[(np * 2 + 1) * 40 + kr] = (ushort_t)(v >> 16);
    }
    __syncthreads();
    half8 a = *(const half8*)&As[(w * 16 + cl) * 40 + q8];
#pragma unroll
    for (int nt = 0; nt < 8; ++nt) {
      half8 bfr = *(const half8*)&Bs[(nt * 16 + cl) * 40 + q8];
      acc[nt] = __builtin_amdgcn_mfma_f32_16x16x32_f16(a, bfr, acc[nt], 0, 0, 0);
    }
    __syncthreads();
  }
#pragma unroll
  for (int nt = 0; nt < 8; ++nt) {
    int col = n0 + nt * 16 + cl;
    float bf = bias[512 + col];
#pragma unroll
    for (int r = 0; r < 4; ++r) {
      int m = m0 + w * 16 + ((lane >> 4) << 2) + r;
      int t = m & 511, b = m >> 9;
      float z = acc[nt][r] + bf;
      float fv = 1.f / (1.f + __expf(-z));
      f_buf[(t * 512 + col) * 64 + b] = (_Float16)fv;
    }
  }
}

// ============ K3: batch-partitioned persistent LSTM scan ============
// 64 blocks = 8 groups (G = bid&7). Producer protocol = R5 exactly (publish
// packed h, vmcnt(0) drain, THEN flag — R7 proved drain-free variants just
// convert the drain into consumer retries). R8 consumer: pipelined
// arrival-order poll+gather+MFMA. kstep kk needs only producer waves
// 2kk,2kk+1; each loop iteration issues {poll load, chunk loads for ksteps
// whose flag-pair was seen last iteration}, waits ONCE (1 RTT covers all),
// MFMAs arrived chunks. Early chunks hide under laggard-producer wait; the
// post-last-flag tail shrinks from [16-load RTT + 51 MFMAs] to
// [1-load RTT + 3 MFMAs]. x-input MFMAs hoisted fully before the poll.
// Degenerates to R5's 2-RTT path when all flags arrive at once.
__global__ __launch_bounds__(256, 1) void k_scan(const _Float16* __restrict__ R16t,
                                                 const float* __restrict__ bias,
                                                 const _Float16* __restrict__ f16,
                                                 const _Float16* __restrict__ x16,
                                                 uint_t* hb, uint_t* flg,
                                                 float* __restrict__ out) {
  const int tid = threadIdx.x;
  const int bid = blockIdx.x;         // 0..63
  const int G = bid & 7;              // group (batch tile)
  const int mj = bid >> 3;            // member block 0..7
  const int lane = tid & 63, w = tid >> 6;
  const int cl = lane & 15, quad = lane >> 4, q8 = quad * 8;
  const int widx = (mj << 2) | w;     // producer-wave index in group, 0..31
  const int u0 = widx * 16;           // unit tile base
  const int u = u0 + cl;              // this lane's unit
  const int b0 = G * 8;               // batch base
  const int arow = b0 + (cl & 7);     // A-frag batch row (rows 8..15 duplicate)

  // B fragments: 3 gates (i,c,o) x 17 ksteps = 204 VGPRs
  half8 bfr[3][17];
#pragma unroll
  for (int g3 = 0; g3 < 3; ++g3)
#pragma unroll
    for (int kk = 0; kk < 17; ++kk)
#pragma unroll
      for (int jj = 0; jj < 8; ++jj)
        bfr[g3][kk][jj] = R16t[(kk * 32 + q8 + jj) * 1536 + g3 * 512 + u];

  const float bi = bias[u];
  const float bc = bias[1024 + u];
  const float bo = bias[1536 + u];
  float c_st[4] = {0.f, 0.f, 0.f, 0.f};

#pragma unroll 1
  for (int t = 0; t < T_; ++t) {
    // ---- t-dependent, h-independent prefetch (before any waiting) ----
    float fpre[4];
    {
      union { ull_t q; _Float16 h[4]; } fu;
      fu.q = *(const ull_t*)(f16 + ((t * 512 + u) * 64 + b0 + (quad & 1) * 4));
#pragma unroll
      for (int r = 0; r < 4; ++r) fpre[r] = (float)fu.h[r];
    }
    half8 xa = *(const half8*)(x16 + ((t * 64 + arow) * 32 + q8));

    // ---- hoisted x-input MFMAs (kstep 16): no h dependence ----
    f32x4 ai = f32x4{0.f, 0.f, 0.f, 0.f};
    f32x4 ac = f32x4{0.f, 0.f, 0.f, 0.f};
    f32x4 ao = f32x4{0.f, 0.f, 0.f, 0.f};
    ai = __builtin_amdgcn_mfma_f32_16x16x32_f16(xa, bfr[0][16], ai, 0, 0, 0);
    ac = __builtin_amdgcn_mfma_f32_16x16x32_f16(xa, bfr[1][16], ac, 0, 0, 0);
    ao = __builtin_amdgcn_mfma_f32_16x16x32_f16(xa, bfr[2][16], ao, 0, 0, 0);

    uint_t* hb_w32 = hb + ((t & 1) ? 0 : 16384);

    if (t > 0) {
      // ---- pipelined arrival-order poll + chunked gather + MFMA ----
      const uint_t* fp = flg + (((t - 1) * 8 + G) << 5) + (lane & 31);
      const char* hb_r = (const char*)hb + ((t & 1) ? 65536 : 0) + arow * 1024 + q8 * 2;
      half8 ga[16];
      uint_t pend = 0xffffu;    // ksteps 0..15 not yet MFMA'd
      uint_t infl = 0u;         // ksteps whose loads are in flight
      uint_t pollv = 0u;
      int guard = 0;
      for (;;) {
        // poll load (fresh, cache-bypassing); chunk loads from last iter in flight
        asm volatile("global_load_dword %0, %1, off sc0 sc1"
                     : "=&v"(pollv) : "v"(fp) : "memory");
        asm volatile("s_waitcnt vmcnt(0)" ::: "memory");
        __builtin_amdgcn_sched_barrier(0);
        if (infl) {
#define DOMFMA(kk) \
          if (infl & (1u << kk)) { \
            ai = __builtin_amdgcn_mfma_f32_16x16x32_f16(ga[kk], bfr[0][kk], ai, 0, 0, 0); \
            ac = __builtin_amdgcn_mfma_f32_16x16x32_f16(ga[kk], bfr[1][kk], ac, 0, 0, 0); \
            ao = __builtin_amdgcn_mfma_f32_16x16x32_f16(ga[kk], bfr[2][kk], ao, 0, 0, 0); }
          DOMFMA(0)  DOMFMA(1)  DOMFMA(2)  DOMFMA(3)
          DOMFMA(4)  DOMFMA(5)  DOMFMA(6)  DOMFMA(7)
          DOMFMA(8)  DOMFMA(9)  DOMFMA(10) DOMFMA(11)
          DOMFMA(12) DOMFMA(13) DOMFMA(14) DOMFMA(15)
#undef DOMFMA
          pend &= ~infl;
          infl = 0u;
        }
        if (!pend) break;
        ull_t bal = __ballot((lane < 32) ? (pollv != 0u) : 1);
        uint_t rdy = 0u;
#pragma unroll
        for (int kk = 0; kk < 16; ++kk)
          rdy |= (((bal >> (2 * kk)) & 3ull) == 3ull) ? (1u << kk) : 0u;
        uint_t newly = rdy & pend;
        if (newly) {
#define GLD(kk, off) \
          if (newly & (1u << kk)) \
            asm volatile("global_load_dwordx4 %0, %1, off offset:" #off " sc0 sc1" \
                         : "=&v"(ga[kk]) : "v"(hb_r));
          GLD(0, 0)    GLD(1, 64)   GLD(2, 128)  GLD(3, 192)
          GLD(4, 256)  GLD(5, 320)  GLD(6, 384)  GLD(7, 448)
          GLD(8, 512)  GLD(9, 576)  GLD(10, 640) GLD(11, 704)
          GLD(12, 768) GLD(13, 832) GLD(14, 896) GLD(15, 960)
#undef GLD
          infl = newly;
        }
        if (++guard > (1 << 20)) break;  // hang-proofing: unreachable in practice
      }
    }

    // ---- epilogue: gates -> c,h (rows brow<8 are the real batches) ----
#pragma unroll
    for (int r = 0; r < 4; ++r) {
      int brow = (quad << 2) + r;   // local batch row 0..15, valid < 8
      float iv = 1.f / (1.f + __expf(-(ai[r] + bi)));
      float cv = 1.f - 2.f / (__expf(2.f * (ac[r] + bc)) + 1.f);
      float ov = 1.f / (1.f + __expf(-(ao[r] + bo)));
      float c = fpre[r] * c_st[r] + iv * cv;
      c_st[r] = c;
      float h = ov * (1.f - 2.f / (__expf(2.f * c) + 1.f));
      if (t < T_ - 1) {
        ushort_t hu = __builtin_bit_cast(ushort_t, (_Float16)h);
        uint_t nbr = (uint_t)(unsigned)__shfl_xor((int)hu, 1);
        uint_t packed = ((uint_t)hu & 0xffffu) | (nbr << 16);
        if (brow < 8 && !(cl & 1)) {
          int hidx = ((b0 + brow) << 8) + ((u0 + cl) >> 1);  // dword index
          __hip_atomic_store(&hb_w32[hidx], packed, __ATOMIC_RELAXED,
                             __HIP_MEMORY_SCOPE_AGENT);
        }
      } else {
        if (brow < 8) out[((b0 + brow) << 9) + u] = h;
      }
    }
    // ---- drain own stores (data committed), then publish flag ----
    asm volatile("s_waitcnt vmcnt(0)" ::: "memory");
    if (lane == 0 && t < T_ - 1)
      __hip_atomic_store(&flg[((t * 8 + G) << 5) + widx], 1u, __ATOMIC_RELAXED,
                         __HIP_MEMORY_SCOPE_AGENT);
  }
}

extern "C" void kernel_launch(void* const* d_in, const int* in_sizes, int n_in,
                              void* d_out, int out_size, void* d_ws, size_t ws_size,
                              hipStream_t stream) {
  const float* x = (const float*)d_in[0];
  const float* ik = (const float*)d_in[1];
  const float* rk = (const float*)d_in[2];
  const float* fk = (const float*)d_in[3];
  const float* bias = (const float*)d_in[4];
  char* ws = (char*)d_ws;
  _Float16* sig = (_Float16*)(ws + SIG_OFF);
  _Float16* f_buf = (_Float16*)(ws + F_OFF);
  uint_t* flg = (uint_t*)(ws + FLG_OFF);
  float* a_buf = (float*)(ws + A_OFF);
  float* dx_buf = (float*)(ws + DX_OFF);
  _Float16* x16 = (_Float16*)(ws + X16_OFF);
  _Float16* R16t = (_Float16*)(ws + R16_OFF);
  _Float16* Wf16 = (_Float16*)(ws + WF16_OFF);
  uint_t* hb = (uint_t*)(ws + HB_OFF);
  float* out = (float*)d_out;

  hipLaunchKernelGGL(k_prep, dim3(68), dim3(256), 0, stream, x, x16, a_buf, dx_buf, hb, flg);
  hipLaunchKernelGGL(k_weights, dim3(1344), dim3(256), 0, stream, rk, ik, fk, R16t, Wf16);
  hipLaunchKernelGGL(k_sig, dim3(64), dim3(1024), 0, stream, a_buf, dx_buf, sig);
  hipLaunchKernelGGL(k_fgemm, dim3(512, 4), dim3(256), 0, stream, sig, Wf16, bias, f_buf);
  hipLaunchKernelGGL(k_scan, dim3(64), dim3(256), 0, stream, R16t, bias, f_buf,
                     x16, hb, flg, out);
}